// Round 7
// baseline (288.719 us; speedup 1.0000x reference)
//
#include <hip/hip_runtime.h>
#include <stdint.h>

typedef __bf16 bf16;
typedef __bf16 bf16x8 __attribute__((ext_vector_type(8)));
typedef float  f32x4  __attribute__((ext_vector_type(4)));

#if __has_builtin(__builtin_amdgcn_exp2f)
#define EXP2F(x) __builtin_amdgcn_exp2f(x)
#else
#define EXP2F(x) exp2f(x)
#endif

constexpr int Bn = 8192, Sn = 256, Rn = 8192;
constexpr int BM = 64, BK = 32, KP = 4;
constexpr int KLEN = Rn / KP;  // 2048
constexpr int NC = KLEN / BK;  // 64 chunks per block

// ---------- prep: type-sort scan (in-LDS, per-block) + inc->bf16 tiled + params + perb ----------
// Each block independently computes the type-sorted permutation in LDS (redundant but
// parallel — kills the serialized 1-block build_perm kernel). Strided ownership
// {i*256+t} makes the count phase LDS-conflict-free; order is deterministic.
// incb layout: [kt][row][32] bf16, kt = sorted-chunk 0..255 (global-chunk-linear).
__global__ __launch_bounds__(256) void prep_all(
    const float* __restrict__ inc, bf16* __restrict__ incb,
    const float* __restrict__ alpha, const float* __restrict__ beta,
    const float* __restrict__ gam, const int* __restrict__ rm, const int* __restrict__ rtype,
    float4* __restrict__ params, const float* __restrict__ temp,
    const float* __restrict__ cr, const float* __restrict__ fuv, float4* __restrict__ perb,
    int* __restrict__ counters) {
  __shared__ __align__(16) float row_lds[8192];   // 32 KB (stage: rtype ints, then inc floats)
  __shared__ unsigned short perm_lds[8192];       // 16 KB
  __shared__ int c0[256], c1[256], c2[256];
  const int g = blockIdx.x, t = threadIdx.x;

  // 1) stage rtype -> LDS (coalesced int4)
  int* rt = (int*)row_lds;
  {
    const int4* src = (const int4*)rtype;
    int4* dst = (int4*)rt;
#pragma unroll
    for (int i = 0; i < 8; ++i) dst[i * 256 + t] = src[i * 256 + t];
  }
  __syncthreads();

  // 2) count (thread t owns r = i*256+t -> conflict-free LDS reads), scan, write perm
  int ty[32];
  int l0 = 0, l1 = 0, l2 = 0;
#pragma unroll
  for (int i = 0; i < 32; ++i) {
    int v = rt[i * 256 + t];
    ty[i] = v;
    l0 += (v == 0); l1 += (v == 1); l2 += (v == 2);
  }
  c0[t] = l0; c1[t] = l1; c2[t] = l2;
  __syncthreads();
  for (int off = 1; off < 256; off <<= 1) {
    int a = (t >= off) ? c0[t - off] : 0;
    int b = (t >= off) ? c1[t - off] : 0;
    int c = (t >= off) ? c2[t - off] : 0;
    __syncthreads();
    c0[t] += a; c1[t] += b; c2[t] += c;
    __syncthreads();
  }
  const int tot0 = c0[255], tot1 = c1[255];
  int o0 = c0[t] - l0;                  // exclusive offsets per bucket
  int o1 = tot0 + c1[t] - l1;
  int o2 = tot0 + tot1 + c2[t] - l2;
#pragma unroll
  for (int i = 0; i < 32; ++i) {
    int v = ty[i];
    int pos = (v == 0) ? o0++ : ((v == 1) ? o1++ : o2++);
    perm_lds[pos] = (unsigned short)(i * 256 + t);
  }
  __syncthreads();

  // 3) params / perb / counter-zero (rt[] still valid; perm_lds ready)
  if (g < 32) {
    int p = g * 256 + t;
    int r = perm_lds[p];
    float a = alpha[r], be = beta[r], gm = gam[r];
    int tv = rt[r];
    int i0 = rm[2 * r], i1 = rm[2 * r + 1];
    float x, P = 0.0f, Q = 0.0f;
    if (tv == 0) { x = __log2f(a); P = be; Q = gm; }       // exp2(x + P*l2t - Q*itv)
    else if (tv == 1) { x = a; }                            // x * cr
    else { x = a * expf(-gm); }                             // x * fuv
    uint32_t bits = (uint32_t)i0 | ((uint32_t)i1 << 10) | ((uint32_t)tv << 20);
    params[p] = make_float4(x, P, Q, __uint_as_float(bits));
  } else if (g < 64) {
    int b = (g - 32) * 256 + t;
    float T = temp[b];
    perb[b] = make_float4(__log2f(T * (1.0f / 300.0f)), 1.4426950408889634f / T,
                          cr[b], fuv[b]);
  } else if (g == 64 && t < 128) {
    counters[t] = 0;  // re-arm split-K tile counters each launch (stream-ordered)
  }
  __syncthreads();

  // 4) stage inc row g (32 KB, coalesced)
  {
    const float4* src = (const float4*)(inc + ((size_t)g << 13));
    float4* dst = (float4*)row_lds;
#pragma unroll
    for (int i = 0; i < 8; ++i) dst[i * 256 + t] = src[i * 256 + t];
  }
  __syncthreads();

  // 5) gather permuted columns -> incb[kt=t][row=g][32]
  const unsigned short* pp = perm_lds + t * 32;
  bf16* outp = incb + ((size_t)t * 256 + g) * 32;
#pragma unroll
  for (int k8 = 0; k8 < 4; ++k8) {
    bf16x8 o;
#pragma unroll
    for (int i = 0; i < 8; ++i) o[i] = (bf16)row_lds[pp[k8 * 8 + i]];
    *(bf16x8*)(outp + k8 * 8) = o;
  }
}

// ---------- fused flux + GEMM + last-arriver split-K reduce ----------
__global__ __launch_bounds__(256, 2) void flux_gemm(
    const float* __restrict__ abund, const float4* __restrict__ perb,
    const float4* __restrict__ params, const bf16* __restrict__ incb,
    float* __restrict__ partial, float* __restrict__ out, int* __restrict__ counters) {
  __shared__ bf16 ab_lds[257 * 64];        // 32,896 B: [s][b]
  __shared__ bf16 flux_lds[2][64 * BK];    // 8,192 B:  [m][k], octets XOR-swizzled
  __shared__ int is_last;

  const int tid  = threadIdx.x;
  const int lane = tid & 63;
  const int w    = tid >> 6;
  const int ws   = __builtin_amdgcn_readfirstlane(w);  // provably-uniform warp id
  // XCD-aware: consecutive blockIdx round-robins XCDs; same-XCD blocks share kp
  const int x   = blockIdx.x & 7;
  const int jb  = blockIdx.x >> 3;         // 0..63
  const int kp  = x & 3;
  const int m0g = (jb * 2 + (x >> 2)) * BM;
  const int kstart = kp * KLEN;
  const int r16 = lane & 15, q = lane >> 4;
  const int sw16 = (r16 >> 1) & 3;         // flux frag-read swizzle
  const int fsw  = w ^ ((lane >> 1) & 3);  // flux-write swizzle

  // stage abundances tile transposed [s][b] (once per block)
  {
    int bsub = tid >> 2;
    int scol = (tid & 3) * 64;
    const float* rowp = abund + (size_t)(m0g + bsub) * Sn + scol;
#pragma unroll
    for (int j = 0; j < 16; ++j) {
      float4 v = *(const float4*)(rowp + j * 4);
      int s = scol + j * 4;
      ab_lds[(s + 0) * 64 + bsub] = (bf16)v.x;
      ab_lds[(s + 1) * 64 + bsub] = (bf16)v.y;
      ab_lds[(s + 2) * 64 + bsub] = (bf16)v.z;
      ab_lds[(s + 3) * 64 + bsub] = (bf16)v.w;
    }
    if (tid < 64) ab_lds[256 * 64 + tid] = (bf16)1.0f;  // ones row (species index S)
  }

  float4 pb = perb[m0g + lane];
  const float l2t = pb.x, nitv = -pb.y, crv = pb.z, fuvv = pb.w;

  // flux tile: flux[b=lane][r = kb + ws*8 + j]; octets type-pure after sort.
  auto flux_tile = [&](int kb, int buf) {
    const float4* pw = params + kb + ws * 8;
    float4 pr[8];
#pragma unroll
    for (int j = 0; j < 8; ++j) pr[j] = pw[j];
    uint32_t b0 = __builtin_amdgcn_readfirstlane(__float_as_uint(pr[0].w));
    uint32_t b7 = __builtin_amdgcn_readfirstlane(__float_as_uint(pr[7].w));
    uint32_t t0 = b0 >> 20, t7 = b7 >> 20;
    bf16x8 fv;
    if (t0 == 0 && t7 == 0) {
#pragma unroll
      for (int j = 0; j < 8; ++j) {
        uint32_t bits = __builtin_amdgcn_readfirstlane(__float_as_uint(pr[j].w));
        int i0 = (int)(bits & 1023), i1 = (int)((bits >> 10) & 1023);
        float a0 = (float)ab_lds[i0 * 64 + lane];
        float a1 = (float)ab_lds[i1 * 64 + lane];
        float v = EXP2F(fmaf(pr[j].y, l2t, fmaf(pr[j].z, nitv, pr[j].x)));
        fv[j] = (bf16)(v * (a0 * a1));
      }
    } else if (t0 == t7) {
      float mv = (t0 == 1) ? crv : fuvv;
#pragma unroll
      for (int j = 0; j < 8; ++j) {
        uint32_t bits = __builtin_amdgcn_readfirstlane(__float_as_uint(pr[j].w));
        int i0 = (int)(bits & 1023), i1 = (int)((bits >> 10) & 1023);
        float a0 = (float)ab_lds[i0 * 64 + lane];
        float a1 = (float)ab_lds[i1 * 64 + lane];
        fv[j] = (bf16)((pr[j].x * mv) * (a0 * a1));
      }
    } else {
#pragma unroll
      for (int j = 0; j < 8; ++j) {
        uint32_t bits = __builtin_amdgcn_readfirstlane(__float_as_uint(pr[j].w));
        int i0 = (int)(bits & 1023), i1 = (int)((bits >> 10) & 1023), ms = (int)(bits >> 20);
        float a0 = (float)ab_lds[i0 * 64 + lane];
        float a1 = (float)ab_lds[i1 * 64 + lane];
        float ve = EXP2F(fmaf(pr[j].y, l2t, fmaf(pr[j].z, nitv, pr[j].x)));
        float vm = pr[j].x * ((ms == 1) ? crv : fuvv);
        float v = (ms == 0) ? ve : vm;
        fv[j] = (bf16)(v * (a0 * a1));
      }
    }
    *(bf16x8*)(flux_lds[buf] + lane * BK + fsw * 8) = fv;
  };

  __syncthreads();  // ab ready

  flux_tile(kstart, 0);

  f32x4 acc[4][4];
#pragma unroll
  for (int i = 0; i < 4; ++i)
#pragma unroll
    for (int j = 0; j < 4; ++j) acc[i][j] = (f32x4)0.0f;

  // per-lane B base in tiled incb: tile (chunk) at chunk*8192; lane reads row
  // (w*64 + nt*16 + r16), 16B at col q*8 -> 1KB coalesced per frag.
  const bf16* bbase = incb + (size_t)(kstart / BK) * 8192 + (w * 64 + r16) * BK + q * 8;

  for (int c = 0; c < NC; ++c) {
    const int cur = c & 1, nxt = cur ^ 1;
    __syncthreads();  // flux_lds[cur] ready

    bf16x8 bfr[4];
    const bf16* bp = bbase + (size_t)c * 8192;
#pragma unroll
    for (int nt = 0; nt < 4; ++nt)
      bfr[nt] = *(const bf16x8*)(bp + nt * (16 * BK));

    bf16x8 af[4];
#pragma unroll
    for (int mt = 0; mt < 4; ++mt)
      af[mt] = *(const bf16x8*)(flux_lds[cur] + (mt * 16 + r16) * BK + (q ^ sw16) * 8);

    if (c + 1 < NC) flux_tile(kstart + (c + 1) * BK, nxt);

    __builtin_amdgcn_s_setprio(1);
#pragma unroll
    for (int mt = 0; mt < 4; ++mt)
#pragma unroll
      for (int nt = 0; nt < 4; ++nt)
        acc[mt][nt] = __builtin_amdgcn_mfma_f32_16x16x32_bf16(af[mt], bfr[nt], acc[mt][nt], 0, 0, 0);
    __builtin_amdgcn_s_setprio(0);
  }

  // epilogue 1: store split-K partial slice (plain stores)
  float* pout = partial + (size_t)kp * Bn * Sn;
#pragma unroll
  for (int mt = 0; mt < 4; ++mt)
#pragma unroll
    for (int nt = 0; nt < 4; ++nt) {
      int col = w * 64 + nt * 16 + r16;
      int row = m0g + mt * 16 + q * 4;
#pragma unroll
      for (int rg = 0; rg < 4; ++rg)
        pout[(size_t)(row + rg) * Sn + col] = acc[mt][nt][rg];
    }

  // epilogue 2: last-arriver reduces this m-tile in FIXED kp order (deterministic)
  __threadfence();   // release: L2 writeback so other XCDs see our partial
  __syncthreads();
  const int tile = jb * 2 + (x >> 2);  // 0..127
  if (tid == 0) is_last = (atomicAdd(&counters[tile], 1) == KP - 1);
  __syncthreads();
  if (is_last) {
    __threadfence();  // acquire: invalidate stale L2 lines before reading partials
    const float4* p4 = (const float4*)partial;
    float4* o4 = (float4*)out;
    constexpr size_t NS4 = (size_t)Bn * Sn / 4;
    const size_t base = (size_t)m0g * (Sn / 4);
#pragma unroll
    for (int ii = 0; ii < 16; ++ii) {
      size_t f = base + (size_t)ii * 256 + tid;
      float4 a = p4[f];
      float4 b = p4[NS4 + f];
      float4 c = p4[2 * NS4 + f];
      float4 d = p4[3 * NS4 + f];
      float4 r;
      r.x = (a.x + b.x) + (c.x + d.x);
      r.y = (a.y + b.y) + (c.y + d.y);
      r.z = (a.z + b.z) + (c.z + d.z);
      r.w = (a.w + b.w) + (c.w + d.w);
      o4[f] = r;
    }
  }
}

// ---------- launch: 2 kernels ----------
extern "C" void kernel_launch(void* const* d_in, const int* in_sizes, int n_in,
                              void* d_out, int out_size, void* d_ws, size_t ws_size,
                              hipStream_t stream) {
  const float* abund = (const float*)d_in[1];
  const float* temp  = (const float*)d_in[2];
  const float* cr    = (const float*)d_in[3];
  const float* fuv   = (const float*)d_in[4];
  const float* inc   = (const float*)d_in[5];
  const float* alpha = (const float*)d_in[6];
  const float* beta  = (const float*)d_in[7];
  const float* gam   = (const float*)d_in[8];
  const int*   rm    = (const int*)d_in[9];
  const int*   rty   = (const int*)d_in[10];
  float* out = (float*)d_out;

  // ws: params f4[8192] | perb f4[8192] | incb bf16[2M] | partial f32[4*2M] | counters
  float4* params  = (float4*)d_ws;
  float4* perb    = params + Rn;
  bf16*   incb    = (bf16*)(perb + Bn);
  float*  partial = (float*)(incb + (size_t)Sn * Rn);
  int*    counters = (int*)(partial + (size_t)KP * Bn * Sn);

  prep_all<<<256, 256, 0, stream>>>(inc, incb, alpha, beta, gam, rm, rty,
                                    params, temp, cr, fuv, perb, counters);
  flux_gemm<<<(Bn / BM) * KP, 256, 0, stream>>>(abund, perb, params, incb,
                                                partial, out, counters);
}

// Round 8
// 154.186 us; speedup vs baseline: 1.8725x; 1.8725x over previous
//
#include <hip/hip_runtime.h>
#include <stdint.h>

typedef __bf16 bf16;
typedef __bf16 bf16x8 __attribute__((ext_vector_type(8)));
typedef float  f32x4  __attribute__((ext_vector_type(4)));

#if __has_builtin(__builtin_amdgcn_exp2f)
#define EXP2F(x) __builtin_amdgcn_exp2f(x)
#else
#define EXP2F(x) exp2f(x)
#endif

constexpr int Bn = 8192, Sn = 256, Rn = 8192;
constexpr int BM = 64, BK = 32, KP = 4;
constexpr int KLEN = Rn / KP;  // 2048
constexpr int NC = KLEN / BK;  // 64 chunks per block

// ---------- prep: in-LDS type-sort scan + params + perb + inc->bf16 tiled ----------
// Each block independently computes the type-sorted permutation in LDS (redundant but
// parallel — no serialized 1-block sort kernel, no extra launch).
// incb layout: [kt][row][32] bf16, kt = sorted-chunk 0..255 (global-chunk-linear).
__global__ __launch_bounds__(256) void prep_all(
    const float* __restrict__ inc, bf16* __restrict__ incb,
    const float* __restrict__ alpha, const float* __restrict__ beta,
    const float* __restrict__ gam, const int* __restrict__ rm, const int* __restrict__ rtype,
    float4* __restrict__ params, const float* __restrict__ temp,
    const float* __restrict__ cr, const float* __restrict__ fuv, float4* __restrict__ perb) {
  __shared__ __align__(16) float row_lds[8192];   // 32 KB (stage: rtype ints, then inc floats)
  __shared__ unsigned short perm_lds[8192];       // 16 KB
  __shared__ int c0[256], c1[256], c2[256];
  const int g = blockIdx.x, t = threadIdx.x;

  // 1) stage rtype -> LDS (coalesced int4)
  int* rt = (int*)row_lds;
  {
    const int4* src = (const int4*)rtype;
    int4* dst = (int4*)rt;
#pragma unroll
    for (int i = 0; i < 8; ++i) dst[i * 256 + t] = src[i * 256 + t];
  }
  __syncthreads();

  // 2) count (thread t owns r = i*256+t), scan, write perm
  int ty[32];
  int l0 = 0, l1 = 0, l2 = 0;
#pragma unroll
  for (int i = 0; i < 32; ++i) {
    int v = rt[i * 256 + t];
    ty[i] = v;
    l0 += (v == 0); l1 += (v == 1); l2 += (v == 2);
  }
  c0[t] = l0; c1[t] = l1; c2[t] = l2;
  __syncthreads();
  for (int off = 1; off < 256; off <<= 1) {
    int a = (t >= off) ? c0[t - off] : 0;
    int b = (t >= off) ? c1[t - off] : 0;
    int c = (t >= off) ? c2[t - off] : 0;
    __syncthreads();
    c0[t] += a; c1[t] += b; c2[t] += c;
    __syncthreads();
  }
  const int tot0 = c0[255], tot1 = c1[255];
  int o0 = c0[t] - l0;                  // exclusive offsets per bucket
  int o1 = tot0 + c1[t] - l1;
  int o2 = tot0 + tot1 + c2[t] - l2;
#pragma unroll
  for (int i = 0; i < 32; ++i) {
    int v = ty[i];
    int pos = (v == 0) ? o0++ : ((v == 1) ? o1++ : o2++);
    perm_lds[pos] = (unsigned short)(i * 256 + t);
  }
  __syncthreads();

  // 3) params / perb (rt[] still valid; perm_lds ready)
  if (g < 32) {
    int p = g * 256 + t;
    int r = perm_lds[p];
    float a = alpha[r], be = beta[r], gm = gam[r];
    int tv = rt[r];
    int i0 = rm[2 * r], i1 = rm[2 * r + 1];
    float x, P = 0.0f, Q = 0.0f;
    if (tv == 0) { x = __log2f(a); P = be; Q = gm; }       // exp2(x + P*l2t - Q*itv)
    else if (tv == 1) { x = a; }                            // x * cr
    else { x = a * expf(-gm); }                             // x * fuv
    uint32_t bits = (uint32_t)i0 | ((uint32_t)i1 << 10) | ((uint32_t)tv << 20);
    params[p] = make_float4(x, P, Q, __uint_as_float(bits));
  } else if (g < 64) {
    int b = (g - 32) * 256 + t;
    float T = temp[b];
    perb[b] = make_float4(__log2f(T * (1.0f / 300.0f)), 1.4426950408889634f / T,
                          cr[b], fuv[b]);
  }
  __syncthreads();

  // 4) stage inc row g (32 KB, coalesced)
  {
    const float4* src = (const float4*)(inc + ((size_t)g << 13));
    float4* dst = (float4*)row_lds;
#pragma unroll
    for (int i = 0; i < 8; ++i) dst[i * 256 + t] = src[i * 256 + t];
  }
  __syncthreads();

  // 5) gather permuted columns -> incb[kt=t][row=g][32]
  const unsigned short* pp = perm_lds + t * 32;
  bf16* outp = incb + ((size_t)t * 256 + g) * 32;
#pragma unroll
  for (int k8 = 0; k8 < 4; ++k8) {
    bf16x8 o;
#pragma unroll
    for (int i = 0; i < 8; ++i) o[i] = (bf16)row_lds[pp[k8 * 8 + i]];
    *(bf16x8*)(outp + k8 * 8) = o;
  }
}

// ---------- fused flux + GEMM: register-pipelined B-frags + params, unroll x2 ----------
__global__ __launch_bounds__(256, 2) void flux_gemm(
    const float* __restrict__ abund, const float4* __restrict__ perb,
    const float4* __restrict__ params, const bf16* __restrict__ incb,
    float* __restrict__ partial) {
  __shared__ bf16 ab_lds[257 * 64];        // 32,896 B: [s][b]
  __shared__ bf16 flux_lds[2][64 * BK];    // 8,192 B:  [m][k], octets XOR-swizzled

  const int tid  = threadIdx.x;
  const int lane = tid & 63;
  const int w    = tid >> 6;
  const int ws   = __builtin_amdgcn_readfirstlane(w);  // provably-uniform warp id
  // XCD-aware: consecutive blockIdx round-robins XCDs; same-XCD blocks share kp
  const int x   = blockIdx.x & 7;
  const int jb  = blockIdx.x >> 3;         // 0..63
  const int kp  = x & 3;
  const int m0g = (jb * 2 + (x >> 2)) * BM;
  const int kstart = kp * KLEN;
  const int r16 = lane & 15, q = lane >> 4;
  const int sw16 = (r16 >> 1) & 3;         // flux frag-read swizzle
  const int fsw  = w ^ ((lane >> 1) & 3);  // flux-write swizzle

  // issue params for chunk 0 immediately (hidden behind ab staging)
  float4 pr0[8];
  {
    const float4* pw = params + kstart + ws * 8;
#pragma unroll
    for (int j = 0; j < 8; ++j) pr0[j] = pw[j];
  }

  // stage abundances tile transposed [s][b] (once per block)
  {
    int bsub = tid >> 2;
    int scol = (tid & 3) * 64;
    const float* rowp = abund + (size_t)(m0g + bsub) * Sn + scol;
#pragma unroll
    for (int j = 0; j < 16; ++j) {
      float4 v = *(const float4*)(rowp + j * 4);
      int s = scol + j * 4;
      ab_lds[(s + 0) * 64 + bsub] = (bf16)v.x;
      ab_lds[(s + 1) * 64 + bsub] = (bf16)v.y;
      ab_lds[(s + 2) * 64 + bsub] = (bf16)v.z;
      ab_lds[(s + 3) * 64 + bsub] = (bf16)v.w;
    }
    if (tid < 64) ab_lds[256 * 64 + tid] = (bf16)1.0f;  // ones row (species index S)
  }

  float4 pb = perb[m0g + lane];
  const float l2t = pb.x, nitv = -pb.y, crv = pb.z, fuvv = pb.w;

  // flux tile from preloaded params: flux[b=lane][r = chunk*32 + ws*8 + j]
  auto flux_tile = [&](int buf, const float4* pr) {
    uint32_t b0 = __builtin_amdgcn_readfirstlane(__float_as_uint(pr[0].w));
    uint32_t b7 = __builtin_amdgcn_readfirstlane(__float_as_uint(pr[7].w));
    uint32_t t0 = b0 >> 20, t7 = b7 >> 20;
    bf16x8 fv;
    if (t0 == 0 && t7 == 0) {
#pragma unroll
      for (int j = 0; j < 8; ++j) {
        uint32_t bits = __builtin_amdgcn_readfirstlane(__float_as_uint(pr[j].w));
        int i0 = (int)(bits & 1023), i1 = (int)((bits >> 10) & 1023);
        float a0 = (float)ab_lds[i0 * 64 + lane];
        float a1 = (float)ab_lds[i1 * 64 + lane];
        float v = EXP2F(fmaf(pr[j].y, l2t, fmaf(pr[j].z, nitv, pr[j].x)));
        fv[j] = (bf16)(v * (a0 * a1));
      }
    } else if (t0 == t7) {
      float mv = (t0 == 1) ? crv : fuvv;
#pragma unroll
      for (int j = 0; j < 8; ++j) {
        uint32_t bits = __builtin_amdgcn_readfirstlane(__float_as_uint(pr[j].w));
        int i0 = (int)(bits & 1023), i1 = (int)((bits >> 10) & 1023);
        float a0 = (float)ab_lds[i0 * 64 + lane];
        float a1 = (float)ab_lds[i1 * 64 + lane];
        fv[j] = (bf16)((pr[j].x * mv) * (a0 * a1));
      }
    } else {
#pragma unroll
      for (int j = 0; j < 8; ++j) {
        uint32_t bits = __builtin_amdgcn_readfirstlane(__float_as_uint(pr[j].w));
        int i0 = (int)(bits & 1023), i1 = (int)((bits >> 10) & 1023), ms = (int)(bits >> 20);
        float a0 = (float)ab_lds[i0 * 64 + lane];
        float a1 = (float)ab_lds[i1 * 64 + lane];
        float ve = EXP2F(fmaf(pr[j].y, l2t, fmaf(pr[j].z, nitv, pr[j].x)));
        float vm = pr[j].x * ((ms == 1) ? crv : fuvv);
        float v = (ms == 0) ? ve : vm;
        fv[j] = (bf16)(v * (a0 * a1));
      }
    }
    *(bf16x8*)(flux_lds[buf] + lane * BK + fsw * 8) = fv;
  };

  auto load_params = [&](int chunk, float4* pr) {
    const float4* pw = params + kstart + chunk * BK + ws * 8;
#pragma unroll
    for (int j = 0; j < 8; ++j) pr[j] = pw[j];
  };

  // per-lane B base in tiled incb: chunk tile at chunk*8192; lane reads row
  // (w*64 + nt*16 + r16), 16B at col q*8 -> 1KB coalesced per frag.
  const bf16* bbase = incb + (size_t)(kstart / BK) * 8192 + (w * 64 + r16) * BK + q * 8;
  auto load_bfr = [&](int chunk, bf16x8* bfr) {
    const bf16* bp = bbase + (size_t)chunk * 8192;
#pragma unroll
    for (int nt = 0; nt < 4; ++nt)
      bfr[nt] = *(const bf16x8*)(bp + nt * (16 * BK));
  };

  auto do_mfma = [&](f32x4 (*acc)[4], const bf16x8* af, const bf16x8* bfr) {
    __builtin_amdgcn_s_setprio(1);
#pragma unroll
    for (int mt = 0; mt < 4; ++mt)
#pragma unroll
      for (int nt = 0; nt < 4; ++nt)
        acc[mt][nt] = __builtin_amdgcn_mfma_f32_16x16x32_bf16(af[mt], bfr[nt], acc[mt][nt], 0, 0, 0);
    __builtin_amdgcn_s_setprio(0);
  };

  __syncthreads();  // ab ready

  flux_tile(0, pr0);       // flux chunk 0 -> flux_lds[0]

  float4 prE[8], prO[8];
  bf16x8 bfrA[4], bfrB[4];
  load_bfr(0, bfrA);       // B-frags chunk 0: a full chunk of latency cover

  f32x4 acc[4][4];
#pragma unroll
  for (int i = 0; i < 4; ++i)
#pragma unroll
    for (int j = 0; j < 4; ++j) acc[i][j] = (f32x4)0.0f;

  for (int c = 0; c < NC; c += 2) {
    // ---- even sub-iter: MFMA chunk c (buf0, bfrA); flux chunk c+1 -> buf1
    __syncthreads();                           // flux_lds[0] ready; buf1 reads done
    load_params(c + 1, prE);                   // issue early (c+1 <= 63 always)
    bf16x8 afA[4];
#pragma unroll
    for (int mt = 0; mt < 4; ++mt)
      afA[mt] = *(const bf16x8*)(flux_lds[0] + (mt * 16 + r16) * BK + (q ^ sw16) * 8);
    load_bfr(c + 1, bfrB);                     // lands during this+next chunk
    flux_tile(1, prE);
    do_mfma(acc, afA, bfrA);                   // bfrA loaded a full chunk ago: no wait

    // ---- odd sub-iter: MFMA chunk c+1 (buf1, bfrB); flux chunk c+2 -> buf0
    __syncthreads();                           // flux_lds[1] ready; buf0 reads done
    const int c2 = (c + 2 < NC) ? c + 2 : 0;   // clamp (value unused when c+2==NC)
    load_params(c2, prO);
    bf16x8 afB[4];
#pragma unroll
    for (int mt = 0; mt < 4; ++mt)
      afB[mt] = *(const bf16x8*)(flux_lds[1] + (mt * 16 + r16) * BK + (q ^ sw16) * 8);
    load_bfr(c2, bfrA);
    if (c + 2 < NC) flux_tile(0, prO);
    do_mfma(acc, afB, bfrB);
  }

  // epilogue: plain stores of the split-K partial
  float* pout = partial + (size_t)kp * Bn * Sn;
#pragma unroll
  for (int mt = 0; mt < 4; ++mt)
#pragma unroll
    for (int nt = 0; nt < 4; ++nt) {
      int col = w * 64 + nt * 16 + r16;
      int row = m0g + mt * 16 + q * 4;
#pragma unroll
      for (int rg = 0; rg < 4; ++rg)
        pout[(size_t)(row + rg) * Sn + col] = acc[mt][nt][rg];
    }
}

// ---------- split-K reduce ----------
__global__ __launch_bounds__(256) void reduce_k(const float* __restrict__ partial,
                                               float* __restrict__ out) {
  size_t i = ((size_t)blockIdx.x * 256 + threadIdx.x) * 4;
  constexpr size_t NS = (size_t)Bn * Sn;
  float4 a = *(const float4*)(partial + i);
  float4 b = *(const float4*)(partial + NS + i);
  float4 c = *(const float4*)(partial + 2 * NS + i);
  float4 d = *(const float4*)(partial + 3 * NS + i);
  float4 r;
  r.x = (a.x + b.x) + (c.x + d.x);
  r.y = (a.y + b.y) + (c.y + d.y);
  r.z = (a.z + b.z) + (c.z + d.z);
  r.w = (a.w + b.w) + (c.w + d.w);
  *(float4*)(out + i) = r;
}

// ---------- launch: 3 kernels ----------
extern "C" void kernel_launch(void* const* d_in, const int* in_sizes, int n_in,
                              void* d_out, int out_size, void* d_ws, size_t ws_size,
                              hipStream_t stream) {
  const float* abund = (const float*)d_in[1];
  const float* temp  = (const float*)d_in[2];
  const float* cr    = (const float*)d_in[3];
  const float* fuv   = (const float*)d_in[4];
  const float* inc   = (const float*)d_in[5];
  const float* alpha = (const float*)d_in[6];
  const float* beta  = (const float*)d_in[7];
  const float* gam   = (const float*)d_in[8];
  const int*   rm    = (const int*)d_in[9];
  const int*   rty   = (const int*)d_in[10];
  float* out = (float*)d_out;

  float4* params  = (float4*)d_ws;
  float4* perb    = params + Rn;
  bf16*   incb    = (bf16*)(perb + Bn);
  float*  partial = (float*)(incb + (size_t)Sn * Rn);

  prep_all<<<256, 256, 0, stream>>>(inc, incb, alpha, beta, gam, rm, rty,
                                    params, temp, cr, fuv, perb);
  flux_gemm<<<(Bn / BM) * KP, 256, 0, stream>>>(abund, perb, params, incb, partial);
  reduce_k<<<(Bn * Sn) / 1024, 256, 0, stream>>>(partial, out);
}